// Round 3
// baseline (146.603 us; speedup 1.0000x reference)
//
#include <hip/hip_runtime.h>
#include <math.h>

#define WPB 4                 // waves per block
#define BLOCK_T (WPB * 64)

__device__ __forceinline__ double d2_exact(float ax, float ay, float az,
                                           float bx, float by, float bz) {
    // fp64 on fp32 inputs: diffs exact, squares ~1e-16 rel -> effectively exact ordering
    const double dx = (double)ax - (double)bx;
    const double dy = (double)ay - (double)by;
    const double dz = (double)az - (double)bz;
    return fma(dx, dx, fma(dy, dy, dz * dz));
}

// One wave per output row.
// Rows [0, Nq): per-query Voronoi edge-distance min  -> out[row]
// Rows [Nq, Nq+Mv): per-vpoint 10-NN repulsion       -> out[Nq + r*10 + j]
__global__ __launch_bounds__(BLOCK_T)
void voronoi_kernel(const float* __restrict__ queries,
                    const float* __restrict__ vpoints,
                    float* __restrict__ out,
                    int Nq, int Mv)
{
    __shared__ int s_i[WPB][64];

    const int lane  = threadIdx.x & 63;
    const int wv    = threadIdx.x >> 6;
    const int row   = blockIdx.x * WPB + wv;
    const int total = Nq + Mv;
    if (row >= total) return;               // wave-uniform; no __syncthreads anywhere

    const bool  isq = (row < Nq);
    const float* src = isq ? (queries + 3 * row) : (vpoints + 3 * (row - Nq));
    const float qx = src[0], qy = src[1], qz = src[2];

    // ---- adaptive radius: target ~35 expected candidates, boundary-aware ----
    const float rho = (float)Mv * 0.125f;                 // density over [-1,1]^3
    const float Tt  = 35.0f * 6.0f / (3.14159265f * rho); // target extent product
    float h = 0.5f * cbrtf(Tt);                           // interior guess (2h)^3=Tt
    #pragma unroll
    for (int it = 0; it < 2; ++it) {
        float ex = fminf(qx + h, 1.0f) - fmaxf(qx - h, -1.0f);
        float ey = fminf(qy + h, 1.0f) - fmaxf(qy - h, -1.0f);
        float ez = fminf(qz + h, 1.0f) - fmaxf(qz - h, -1.0f);
        h *= cbrtf(Tt / (ex * ey * ez));
    }
    float tau = h * h;

    // ---- scan + ballot-compact candidate ids (fp32 filter) into wave LDS ----
    // Trip count is WAVE-UNIFORM (all 64 lanes execute every iteration; j<Mv only
    // masks the predicate) so __ballot sees all lanes and cntS/cntL are uniform.
    // strict count (d2 < tau) proves containment of the true top-11; loose admit
    // (d2 < tau + MARGIN) covers fp32-vs-fp64 boundary error (<= ~1.5e-6 abs).
    const float MARGIN = 2e-5f;
    const int   NIT = (Mv + 63) >> 6;
    int cntS = 0, cntL = 0;
    for (int attempt = 0; attempt < 16; ++attempt) {
        cntS = 0; cntL = 0;
        const float tauL = tau + MARGIN;
        for (int t = 0; t < NIT; ++t) {
            const int j = (t << 6) + lane;
            bool ps = false, pl = false;
            if (j < Mv) {
                const float bx = vpoints[3 * j];
                const float by = vpoints[3 * j + 1];
                const float bz = vpoints[3 * j + 2];
                const float dx = qx - bx, dy = qy - by, dz = qz - bz;
                const float d2 = fmaf(dx, dx, fmaf(dy, dy, dz * dz));
                ps = (d2 < tau);
                pl = (d2 < tauL);
            }
            const unsigned long long mS = __ballot(ps);
            const unsigned long long mL = __ballot(pl);
            if (pl) {
                const int off = cntL + (int)__popcll(mL & ((1ULL << lane) - 1ULL));
                if (off < 64) s_i[wv][off] = j;
            }
            cntS += (int)__popcll(mS);
            cntL += (int)__popcll(mL);
        }
        if (cntS >= 11 && cntL <= 64) break;   // wave-uniform now
        tau = (cntS < 11) ? (tau * 2.0f) : (tau * 0.55f);
    }

    // ---- one candidate/lane: recompute d2 in fp64 (exact ordering) ----
    double d  = 1e300;
    int    id = 0x40000000 + lane;          // unique pad ids (> any real id)
    if (lane < cntL) {
        id = s_i[wv][lane];
        const float* b = vpoints + 3 * id;
        d = d2_exact(qx, qy, qz, b[0], b[1], b[2]);
    }

    // ---- 64-lane bitonic sort ascending on (d, id); id tie-break == stable top_k ----
    #pragma unroll
    for (int k = 2; k <= 64; k <<= 1) {
        #pragma unroll
        for (int jj = k >> 1; jj > 0; jj >>= 1) {
            const double od = __shfl_xor(d, jj, 64);
            const int    oi = __shfl_xor(id, jj, 64);
            const bool pless    = (od < d) || (od == d && oi < id);
            const bool want_min = (((lane & k) == 0) == ((lane & jj) == 0));
            const bool take     = (pless == want_min);
            d  = take ? od : d;
            id = take ? oi : id;
        }
    }
    // lane l now holds the (l+1)-th smallest (d, id); lanes 0..10 are the 11-NN.

    if (isq) {
        // ---- Voronoi edge distance: lanes 1..10 each own one edge ----
        const int   idx0 = __shfl(id, 0, 64);
        const float p0x = vpoints[3 * idx0];
        const float p0y = vpoints[3 * idx0 + 1];
        const float p0z = vpoints[3 * idx0 + 2];
        float sq = INFINITY;
        if (lane >= 1 && lane <= 10) {
            const float vx = vpoints[3 * id], vy = vpoints[3 * id + 1], vz = vpoints[3 * id + 2];
            const float ex = vx - p0x, ey = vy - p0y, ez = vz - p0z;
            const float el = sqrtf(ex * ex + ey * ey + ez * ez);
            const float px = qx - p0x, py = qy - p0y, pz = qz - p0z;
            const float vl = (px * ex + py * ey + pz * ez) / el;
            const float t  = vl - 0.5f * el;
            sq = t * t;
        }
        #pragma unroll
        for (int s = 32; s > 0; s >>= 1) sq = fminf(sq, __shfl_xor(sq, s, 64));
        if (lane == 0) out[row] = sq;
    } else {
        // ---- repulsion: drop self (lane 0), ascending d for lanes 1..10 ----
        if (lane >= 1 && lane <= 10) {
            const float v = (float)d;       // matches ref f32 d2 to ~1e-7
            out[Nq + (row - Nq) * 10 + (lane - 1)] = expf(-100.0f * v) / 100.0f;
        }
    }
}

extern "C" void kernel_launch(void* const* d_in, const int* in_sizes, int n_in,
                              void* d_out, int out_size, void* d_ws, size_t ws_size,
                              hipStream_t stream) {
    const float* queries = (const float*)d_in[0];
    const float* vpoints = (const float*)d_in[1];
    float* out = (float*)d_out;
    const int Nq = in_sizes[0] / 3;
    const int Mv = in_sizes[1] / 3;
    const int total_rows = Nq + Mv;
    const int blocks = (total_rows + WPB - 1) / WPB;
    voronoi_kernel<<<blocks, BLOCK_T, 0, stream>>>(queries, vpoints, out, Nq, Mv);
}

// Round 4
// 94.251 us; speedup vs baseline: 1.5555x; 1.5555x over previous
//
#include <hip/hip_runtime.h>
#include <math.h>

#define WPB 4                 // waves per block
#define BLOCK_T (WPB * 64)
#define GX 8
#define GY 8
#define GZ 16
#define NCELL (GX * GY * GZ)  // 1024 cells; z fastest => z-columns are CSR-contiguous

__device__ __forceinline__ double d2_exact(float ax, float ay, float az,
                                           float bx, float by, float bz) {
    const double dx = (double)ax - (double)bx;
    const double dy = (double)ay - (double)by;
    const double dz = (double)az - (double)bz;
    return fma(dx, dx, fma(dy, dy, dz * dz));
}

__device__ __forceinline__ int cell_of(float x, float y, float z) {
    int cx = (int)floorf((x + 1.0f) * (GX * 0.5f)); cx = min(max(cx, 0), GX - 1);
    int cy = (int)floorf((y + 1.0f) * (GY * 0.5f)); cy = min(max(cy, 0), GY - 1);
    int cz = (int)floorf((z + 1.0f) * (GZ * 0.5f)); cz = min(max(cz, 0), GZ - 1);
    return (cx * GY + cy) * GZ + cz;
}

__global__ void k_zero(int* __restrict__ cnt) {
    int t = blockIdx.x * blockDim.x + threadIdx.x;
    if (t < NCELL) cnt[t] = 0;
}

__global__ void k_hist(const float* __restrict__ vp, int* __restrict__ cnt, int Mv) {
    int j = blockIdx.x * blockDim.x + threadIdx.x;
    if (j < Mv) atomicAdd(&cnt[cell_of(vp[3*j], vp[3*j+1], vp[3*j+2])], 1);
}

__global__ __launch_bounds__(NCELL)
void k_scan(const int* __restrict__ cnt, int* __restrict__ off, int* __restrict__ cur) {
    __shared__ int s[NCELL];
    const int t = threadIdx.x;
    const int c = cnt[t];
    s[t] = c;
    __syncthreads();
    #pragma unroll
    for (int d = 1; d < NCELL; d <<= 1) {
        int v = (t >= d) ? s[t - d] : 0;
        __syncthreads();
        s[t] += v;
        __syncthreads();
    }
    const int inc = s[t];
    off[t] = inc - c;
    cur[t] = inc - c;
    if (t == NCELL - 1) off[NCELL] = inc;
}

__global__ void k_scatter(const float* __restrict__ vp, int* __restrict__ cur,
                          float4* __restrict__ pts4, int Mv) {
    int j = blockIdx.x * blockDim.x + threadIdx.x;
    if (j < Mv) {
        const float x = vp[3*j], y = vp[3*j+1], z = vp[3*j+2];
        const int pos = atomicAdd(&cur[cell_of(x, y, z)], 1);
        pts4[pos] = make_float4(x, y, z, __int_as_float(j));
    }
}

// One wave per output row.
// Rows [0, Nq): per-query Voronoi edge-distance min  -> out[row]
// Rows [Nq, Nq+Mv): per-vpoint 10-NN repulsion       -> out[Nq + r*10 + j]
__global__ __launch_bounds__(BLOCK_T)
void voronoi_kernel(const float* __restrict__ queries,
                    const float* __restrict__ vpoints,
                    const float4* __restrict__ pts4,
                    const int* __restrict__ off,
                    float* __restrict__ out,
                    int Nq, int Mv)
{
    __shared__ int s_i[WPB][64];

    const int lane  = threadIdx.x & 63;
    const int wv    = threadIdx.x >> 6;
    const int row   = blockIdx.x * WPB + wv;
    const int total = Nq + Mv;
    if (row >= total) return;               // wave-uniform; no __syncthreads anywhere

    const bool  isq = (row < Nq);
    const float* src = isq ? (queries + 3 * row) : (vpoints + 3 * (row - Nq));
    const float qx = src[0], qy = src[1], qz = src[2];

    // ---- adaptive radius h: target ~35 expected candidates, boundary-aware ----
    const float rho = (float)Mv * 0.125f;
    const float Tt  = 35.0f * 6.0f / (3.14159265f * rho);
    float h = 0.5f * cbrtf(Tt);
    #pragma unroll
    for (int it = 0; it < 2; ++it) {
        float ex = fminf(qx + h, 1.0f) - fmaxf(qx - h, -1.0f);
        float ey = fminf(qy + h, 1.0f) - fmaxf(qy - h, -1.0f);
        float ez = fminf(qz + h, 1.0f) - fmaxf(qz - h, -1.0f);
        h *= cbrtf(Tt / (ex * ey * ez));
    }

    // ---- grid-pruned scan + ballot-compact candidate ids into wave LDS ----
    // Cells covering box [q-h, q+h] cover ball(q,h); strict count (d2 < tau=h^2)
    // >= 11 proves the true top-11 are all admitted (loose margin covers fp32
    // boundary error vs the fp64 sort metric). Rescan adjusts h by factors whose
    // cube (2.0 / 0.51) cannot jump the [11, 64] count window (ratio 5.8).
    const float MARGIN = 2e-5f;
    int cntS = 0, cntL = 0;
    for (int attempt = 0; attempt < 16; ++attempt) {
        cntS = 0; cntL = 0;
        const float tau  = h * h;
        const float tauL = tau + MARGIN;
        int ix0 = (int)floorf((qx - h + 1.0f) * (GX * 0.5f)); ix0 = min(max(ix0, 0), GX - 1);
        int ix1 = (int)floorf((qx + h + 1.0f) * (GX * 0.5f)); ix1 = min(max(ix1, 0), GX - 1);
        int iy0 = (int)floorf((qy - h + 1.0f) * (GY * 0.5f)); iy0 = min(max(iy0, 0), GY - 1);
        int iy1 = (int)floorf((qy + h + 1.0f) * (GY * 0.5f)); iy1 = min(max(iy1, 0), GY - 1);
        int iz0 = (int)floorf((qz - h + 1.0f) * (GZ * 0.5f)); iz0 = min(max(iz0, 0), GZ - 1);
        int iz1 = (int)floorf((qz + h + 1.0f) * (GZ * 0.5f)); iz1 = min(max(iz1, 0), GZ - 1);

        for (int cx = ix0; cx <= ix1; ++cx) {
            for (int cy = iy0; cy <= iy1; ++cy) {
                const int colbase = (cx * GY + cy) * GZ;
                const int s0 = off[colbase + iz0];      // z-contiguous CSR range
                const int e0 = off[colbase + iz1 + 1];
                for (int p0 = s0; p0 < e0; p0 += 64) {  // wave-uniform trip count
                    const int p = p0 + lane;
                    bool ps = false, pl = false;
                    int  pid = 0;
                    if (p < e0) {
                        const float4 pt = pts4[p];
                        const float dx = qx - pt.x, dy = qy - pt.y, dz = qz - pt.z;
                        const float d2 = fmaf(dx, dx, fmaf(dy, dy, dz * dz));
                        pid = __float_as_int(pt.w);
                        ps = (d2 < tau);
                        pl = (d2 < tauL);
                    }
                    const unsigned long long mS = __ballot(ps);
                    const unsigned long long mL = __ballot(pl);
                    if (pl) {
                        const int o = cntL + (int)__popcll(mL & ((1ULL << lane) - 1ULL));
                        if (o < 64) s_i[wv][o] = pid;
                    }
                    cntS += (int)__popcll(mS);
                    cntL += (int)__popcll(mL);
                }
            }
        }
        if (cntS >= 11 && cntL <= 64) break;            // wave-uniform
        h *= (cntS < 11) ? 1.26f : 0.80f;               // count scales ~h^3
    }

    // ---- one candidate/lane: recompute d2 in fp64 (exact ordering) ----
    double d  = 1e300;
    int    id = 0x40000000 + lane;          // unique pad ids (> any real id)
    if (lane < cntL) {
        id = s_i[wv][lane];
        const float* b = vpoints + 3 * id;
        d = d2_exact(qx, qy, qz, b[0], b[1], b[2]);
    }

    // ---- 64-lane bitonic sort ascending on (d, id); id tie-break == stable top_k ----
    #pragma unroll
    for (int k = 2; k <= 64; k <<= 1) {
        #pragma unroll
        for (int jj = k >> 1; jj > 0; jj >>= 1) {
            const double od = __shfl_xor(d, jj, 64);
            const int    oi = __shfl_xor(id, jj, 64);
            const bool pless    = (od < d) || (od == d && oi < id);
            const bool want_min = (((lane & k) == 0) == ((lane & jj) == 0));
            const bool take     = (pless == want_min);
            d  = take ? od : d;
            id = take ? oi : id;
        }
    }
    // lane l holds the (l+1)-th smallest (d, id); lanes 0..10 are the 11-NN.

    if (isq) {
        const int   idx0 = __shfl(id, 0, 64);
        const float p0x = vpoints[3 * idx0];
        const float p0y = vpoints[3 * idx0 + 1];
        const float p0z = vpoints[3 * idx0 + 2];
        float sq = INFINITY;
        if (lane >= 1 && lane <= 10) {
            const float vx = vpoints[3 * id], vy = vpoints[3 * id + 1], vz = vpoints[3 * id + 2];
            const float ex = vx - p0x, ey = vy - p0y, ez = vz - p0z;
            const float el = sqrtf(ex * ex + ey * ey + ez * ez);
            const float px = qx - p0x, py = qy - p0y, pz = qz - p0z;
            const float vl = (px * ex + py * ey + pz * ez) / el;
            const float t  = vl - 0.5f * el;
            sq = t * t;
        }
        #pragma unroll
        for (int s = 32; s > 0; s >>= 1) sq = fminf(sq, __shfl_xor(sq, s, 64));
        if (lane == 0) out[row] = sq;
    } else {
        if (lane >= 1 && lane <= 10) {
            const float v = (float)d;
            out[Nq + (row - Nq) * 10 + (lane - 1)] = expf(-100.0f * v) / 100.0f;
        }
    }
}

extern "C" void kernel_launch(void* const* d_in, const int* in_sizes, int n_in,
                              void* d_out, int out_size, void* d_ws, size_t ws_size,
                              hipStream_t stream) {
    const float* queries = (const float*)d_in[0];
    const float* vpoints = (const float*)d_in[1];
    float* out = (float*)d_out;
    const int Nq = in_sizes[0] / 3;
    const int Mv = in_sizes[1] / 3;

    // workspace layout: pts4[Mv] | cnt[NCELL] | off[NCELL+1] | cur[NCELL]
    char* base = (char*)d_ws;
    float4* pts4 = (float4*)base;
    int* cnt = (int*)(base + (size_t)Mv * sizeof(float4));
    int* off = cnt + NCELL;
    int* cur = off + NCELL + 1;

    k_zero<<<(NCELL + 255) / 256, 256, 0, stream>>>(cnt);
    k_hist<<<(Mv + 255) / 256, 256, 0, stream>>>(vpoints, cnt, Mv);
    k_scan<<<1, NCELL, 0, stream>>>(cnt, off, cur);
    k_scatter<<<(Mv + 255) / 256, 256, 0, stream>>>(vpoints, cur, pts4, Mv);

    const int total_rows = Nq + Mv;
    const int blocks = (total_rows + WPB - 1) / WPB;
    voronoi_kernel<<<blocks, BLOCK_T, 0, stream>>>(queries, vpoints, pts4, off,
                                                   out, Nq, Mv);
}